// Round 1
// baseline (59.645 us; speedup 1.0000x reference)
//
#include <hip/hip_runtime.h>

// RandWarpAug: B=512, C=12, T=4096, DS=4, STEPS=7, KS=51
// in[0] = source   [512,12,4096] f32
// in[1] = flow_mag [1]           f32
// in[2] = noise    [512,1,4096]  f32
// in[3] = smooth_kernel [51]     f32
// out   = [512,12,4096] f32

#define BB 512
#define CC 12
#define TT 4096
#define TD 1024
#define KS 51
#define NT 256

struct WarpW { int y0c, y1c; float w0, w1; };

// Faithful replication of reference warp_1d coordinate math for one sample.
template <int TLEN>
__device__ __forceinline__ WarpW warp_weights(int t, float flow) {
    const float tm1 = (float)(TLEN - 1);
    float nl = (float)t + flow;                 // new_locs
    float v  = 2.0f * (nl / tm1 - 0.5f);        // normalized
    float ix = (v + 1.0f) * 0.5f;               // W=2 -> (W-1)=1
    float iy = ix * tm1;
    float x0 = floorf(ix);
    float fx = ix - x0;
    int   x0i = (int)x0;
    float m0 = (x0i >= 0 && x0i <= 1) ? 1.0f : 0.0f;
    float m1 = (x0i + 1 >= 0 && x0i + 1 <= 1) ? 1.0f : 0.0f;
    float xw = (1.0f - fx) * m0 + fx * m1;
    float y0 = floorf(iy);
    float fy = iy - y0;
    int   y0i = (int)y0;
    int   y1i = y0i + 1;
    float vy0 = (y0i >= 0 && y0i < TLEN) ? 1.0f : 0.0f;
    float vy1 = (y1i >= 0 && y1i < TLEN) ? 1.0f : 0.0f;
    WarpW r;
    r.y0c = min(max(y0i, 0), TLEN - 1);
    r.y1c = min(max(y1i, 0), TLEN - 1);
    r.w0 = xw * (1.0f - fy) * vy0;
    r.w1 = xw * fy * vy1;
    return r;
}

extern "C" __global__ void __launch_bounds__(NT)
rand_warp_aug_kernel(const float* __restrict__ source,
                     const float* __restrict__ flow_mag,
                     const float* __restrict__ noise,
                     const float* __restrict__ gk,
                     float* __restrict__ out) {
    __shared__ float vecA[TD];
    __shared__ float vecB[TD];
    __shared__ float pf_up[TT];
    __shared__ float pf_sm[TT];
    __shared__ float g[KS];

    const int b   = blockIdx.x;
    const int tid = threadIdx.x;
    const float fm = flow_mag[0];

    // ---- phase 1: flow_field = fm*noise; downsample x4 (w=0.5 at 4i+1,4i+2);
    //      * 0.25 (resize_transform factor<1) * 1/128 (VecInt scaling) ----
    const float* nrow = noise + (size_t)b * TT;
    for (int i = tid; i < TD; i += NT) {
        float x1 = fm * nrow[4 * i + 1];
        float x2 = fm * nrow[4 * i + 2];
        // (0.5*x1 + 0.5*x2) * 0.25 * (1/128)  -- power-of-two scalings exact
        vecA[i] = (x1 * 0.5f + x2 * 0.5f) * (0.25f * 0.0078125f);
    }
    if (tid < KS) g[tid] = gk[tid];
    __syncthreads();

    // ---- phase 2: VecInt scaling-and-squaring, 7 steps, Tlen=1024 ----
    float* cur = vecA;
    float* nxt = vecB;
    for (int s = 0; s < 7; ++s) {
        for (int i = tid; i < TD; i += NT) {
            float fl = cur[i];
            WarpW w = warp_weights<TD>(i, fl);
            float g0 = cur[w.y0c];
            float g1 = cur[w.y1c];
            nxt[i] = fl + (w.w0 * g0 + w.w1 * g1);
        }
        __syncthreads();
        float* tmp = cur; cur = nxt; nxt = tmp;
    }
    // final vec is in `cur`

    // ---- phase 3: upsample x4 with magnitude rescale (x4) ----
    for (int j = tid; j < TT; j += NT) {
        float srcp = ((float)j + 0.5f) / 4.0f - 0.5f;
        srcp = fminf(fmaxf(srcp, 0.0f), (float)(TD - 1));
        float flp = floorf(srcp);
        int   i0  = (int)flp;
        int   i1  = min(i0 + 1, TD - 1);
        float w   = srcp - flp;
        float a0  = 4.0f * cur[i0];
        float a1  = 4.0f * cur[i1];
        pf_up[j] = a0 * (1.0f - w) + a1 * w;
    }
    __syncthreads();

    // ---- phase 4: 51-tap conv (cross-correlation), zero padding ----
    for (int t = tid; t < TT; t += NT) {
        float acc = 0.0f;
        int lo = t - (KS - 1) / 2;
#pragma unroll
        for (int k = 0; k < KS; ++k) {
            int idx = lo + k;
            float xv = (idx >= 0 && idx < TT) ? pf_up[idx] : 0.0f;
            acc += xv * g[k];
        }
        pf_sm[t] = acc;
    }
    __syncthreads();

    // ---- phase 5: final warp of source over 12 channels ----
    const float* sbase = source + (size_t)b * CC * TT;
    float*       obase = out    + (size_t)b * CC * TT;
    for (int t = tid; t < TT; t += NT) {
        WarpW w = warp_weights<TT>(t, pf_sm[t]);
#pragma unroll
        for (int c = 0; c < CC; ++c) {
            const float* srow = sbase + (size_t)c * TT;
            float g0 = srow[w.y0c];
            float g1 = srow[w.y1c];
            obase[(size_t)c * TT + t] = w.w0 * g0 + w.w1 * g1;
        }
    }
}

extern "C" void kernel_launch(void* const* d_in, const int* in_sizes, int n_in,
                              void* d_out, int out_size, void* d_ws, size_t ws_size,
                              hipStream_t stream) {
    const float* source   = (const float*)d_in[0];
    const float* flow_mag = (const float*)d_in[1];
    const float* noise    = (const float*)d_in[2];
    const float* gk       = (const float*)d_in[3];
    float* out = (float*)d_out;

    rand_warp_aug_kernel<<<BB, NT, 0, stream>>>(source, flow_mag, noise, gk, out);
}

// Round 2
// 47.705 us; speedup vs baseline: 1.2503x; 1.2503x over previous
//
#include <hip/hip_runtime.h>

// RandWarpAug: B=512, C=12, T=4096, DS=4, STEPS=7, KS=51
// in[0] = source   [512,12,4096] f32
// in[1] = flow_mag [1]           f32
// in[2] = noise    [512,1,4096]  f32
// in[3] = smooth_kernel [51]     f32
// out   = [512,12,4096] f32

#define BB 512
#define CC 12
#define TT 4096
#define TD 1024
#define KS 51
#define NT 1024

struct WarpW { int y0c, y1c; float w0, w1; };

// Faithful replication of reference warp_1d coordinate math for one sample.
template <int TLEN>
__device__ __forceinline__ WarpW warp_weights(int t, float flow) {
    const float tm1 = (float)(TLEN - 1);
    float nl = (float)t + flow;                 // new_locs
    float v  = 2.0f * (nl / tm1 - 0.5f);        // normalized
    float ix = (v + 1.0f) * 0.5f;               // W=2 -> (W-1)=1
    float iy = ix * tm1;
    float x0 = floorf(ix);
    float fx = ix - x0;
    int   x0i = (int)x0;
    float m0 = (x0i >= 0 && x0i <= 1) ? 1.0f : 0.0f;
    float m1 = (x0i + 1 >= 0 && x0i + 1 <= 1) ? 1.0f : 0.0f;
    float xw = (1.0f - fx) * m0 + fx * m1;
    float y0 = floorf(iy);
    float fy = iy - y0;
    int   y0i = (int)y0;
    int   y1i = y0i + 1;
    float vy0 = (y0i >= 0 && y0i < TLEN) ? 1.0f : 0.0f;
    float vy1 = (y1i >= 0 && y1i < TLEN) ? 1.0f : 0.0f;
    WarpW r;
    r.y0c = min(max(y0i, 0), TLEN - 1);
    r.y1c = min(max(y1i, 0), TLEN - 1);
    r.w0 = xw * (1.0f - fy) * vy0;
    r.w1 = xw * fy * vy1;
    return r;
}

extern "C" __global__ void __launch_bounds__(NT)
rand_warp_aug_kernel(const float* __restrict__ source,
                     const float* __restrict__ flow_mag,
                     const float* __restrict__ noise,
                     const float* __restrict__ gk,
                     float* __restrict__ out) {
    __shared__ float vecA[TD];
    __shared__ float vecB[TD];
    __shared__ float pf_up[TT];
    __shared__ float g[KS];

    const int b   = blockIdx.x;
    const int tid = threadIdx.x;
    const float fm = flow_mag[0];

    // ---- phase 1: flow_field = fm*noise; downsample x4 (w=0.5 at 4i+1,4i+2);
    //      * 0.25 (resize_transform factor<1) * 1/128 (VecInt scaling) ----
    const float* nrow = noise + (size_t)b * TT;
    if (tid < TD) {
        float x1 = fm * nrow[4 * tid + 1];
        float x2 = fm * nrow[4 * tid + 2];
        vecA[tid] = (x1 * 0.5f + x2 * 0.5f) * (0.25f * 0.0078125f);
    }
    if (tid < KS) g[tid] = gk[tid];
    __syncthreads();

    // ---- phase 2: VecInt scaling-and-squaring, 7 steps, Tlen=1024 ----
    float* cur = vecA;
    float* nxt = vecB;
#pragma unroll 1
    for (int s = 0; s < 7; ++s) {
        if (tid < TD) {
            float fl = cur[tid];
            WarpW w = warp_weights<TD>(tid, fl);
            float g0 = cur[w.y0c];
            float g1 = cur[w.y1c];
            nxt[tid] = fl + (w.w0 * g0 + w.w1 * g1);
        }
        __syncthreads();
        float* tmp = cur; cur = nxt; nxt = tmp;
    }
    // final vec is in `cur`

    // ---- phase 3: upsample x4 with magnitude rescale (x4) ----
#pragma unroll
    for (int jj = 0; jj < TT / NT; ++jj) {
        int j = tid + jj * NT;
        float srcp = ((float)j + 0.5f) * 0.25f - 0.5f;
        srcp = fminf(fmaxf(srcp, 0.0f), (float)(TD - 1));
        float flp = floorf(srcp);
        int   i0  = (int)flp;
        int   i1  = min(i0 + 1, TD - 1);
        float w   = srcp - flp;
        float a0  = 4.0f * cur[i0];
        float a1  = 4.0f * cur[i1];
        pf_up[j] = a0 * (1.0f - w) + a1 * w;
    }
    __syncthreads();

    // ---- phase 4+5 fused: 51-tap conv (zero pad) -> warp weights -> gather
    const float* sbase = source + (size_t)b * CC * TT;
    float*       obase = out    + (size_t)b * CC * TT;
#pragma unroll 1
    for (int tt = 0; tt < TT / NT; ++tt) {
        int t = tid + tt * NT;
        float acc = 0.0f;
        int lo = t - (KS - 1) / 2;
#pragma unroll
        for (int k = 0; k < KS; ++k) {
            int idx = lo + k;
            float xv = (idx >= 0 && idx < TT) ? pf_up[idx] : 0.0f;
            acc += xv * g[k];
        }
        WarpW w = warp_weights<TT>(t, acc);
#pragma unroll
        for (int c = 0; c < CC; ++c) {
            const float* srow = sbase + (size_t)c * TT;
            float g0 = srow[w.y0c];
            float g1 = srow[w.y1c];
            obase[(size_t)c * TT + t] = w.w0 * g0 + w.w1 * g1;
        }
    }
}

extern "C" void kernel_launch(void* const* d_in, const int* in_sizes, int n_in,
                              void* d_out, int out_size, void* d_ws, size_t ws_size,
                              hipStream_t stream) {
    const float* source   = (const float*)d_in[0];
    const float* flow_mag = (const float*)d_in[1];
    const float* noise    = (const float*)d_in[2];
    const float* gk       = (const float*)d_in[3];
    float* out = (float*)d_out;

    rand_warp_aug_kernel<<<BB, NT, 0, stream>>>(source, flow_mag, noise, gk, out);
}